// Round 9
// baseline (63.057 us; speedup 1.0000x reference)
//
#include <hip/hip_runtime.h>

// uvs [B=16, J=16, M=512, D=256] fp32. j<8 = u (k=j), j>=8 = v (k=j-8).
// gate_u[b,k,m] = (dot(u[b,k,m,:], colsum(v[b,k])) > 0); symmetric for v.
//
// KEY INSIGHT (missed in R4-R7): the dependency is per-(b,k) only. One block
// per (b,k) pair -> no grid barrier, no multi-kernel, no v re-read from HBM.
// 128 blocks x 1024 threads (16 waves). Per block (slices are 512 KiB each):
//   A: read v once: rows 0-255 -> vreg[16] (AGPR-parked, proven R6/R7),
//      rows 256-383 -> LDS (128 KiB), rows 384-511 -> normal loads (L2
//      retention: 64 KiB/block x 16 blocks/XCD = 1 MiB of 4 MiB L2).
//      Block colsum -> vsum (fixed-order tree, replay-deterministic).
//   B: stream u with NT loads (read-once; don't evict v from L2),
//      gate rows vs vsum, NT store; accumulate usum.
//   C: gate v from regs + LDS + L2 re-read; NT store.
// HBM traffic: 134 MB read + 134 MB write = 268 MB, single dispatch.

#define NBLK 128
#define NTHR 1024
#define LDS_BYTES (128 * 1024 + 16 * 1024)   // v rows 256-383 + reduce buffer

typedef float f32x4 __attribute__((ext_vector_type(4)));

__device__ __forceinline__ float row_gate(f32x4 v, f32x4 s) {
    float p = v.x * s.x + v.y * s.y + v.z * s.z + v.w * s.w;
#pragma unroll
    for (int off = 32; off; off >>= 1) p += __shfl_xor(p, off, 64);
    return (p > 0.f) ? 1.f : 0.f;
}

extern __shared__ unsigned char smem_raw[];

__global__ __launch_bounds__(NTHR) void k_fat(const f32x4* __restrict__ in,
                                              f32x4* __restrict__ out) {
    const int bk = blockIdx.x;              // [0,128) = b*8 + k
    const int b  = bk >> 3, k = bk & 7;
    const int t  = threadIdx.x;
    const int l  = t & 63;                  // lane: owns f32x4 column l
    const int w  = t >> 6;                  // wave [0,16)

    f32x4* vlds = (f32x4*)smem_raw;                      // [128][64] rows 256-383
    f32x4* red  = (f32x4*)(smem_raw + 128 * 1024);       // [1024] reduce buf

    const size_t uslice = (size_t)((b * 16 + k) * 512) * 64;
    const size_t vslice = (size_t)((b * 16 + 8 + k) * 512) * 64;

    // ---- Phase A: read v once; park on-chip; block colsum ----
    f32x4 vreg[16];
    f32x4 acc = {0.f, 0.f, 0.f, 0.f};
    {
        const f32x4* p0 = in + vslice + (size_t)(w * 16) * 64 + l;        // rows 0-255
#pragma unroll
        for (int i = 0; i < 16; ++i) {
            vreg[i] = __builtin_nontemporal_load(p0 + (size_t)i * 64);
            acc += vreg[i];
        }
        const f32x4* p1 = in + vslice + (size_t)(256 + w * 8) * 64 + l;   // rows 256-383
#pragma unroll
        for (int i = 0; i < 8; ++i) {
            f32x4 x = __builtin_nontemporal_load(p1 + (size_t)i * 64);
            acc += x;
            vlds[(w * 8 + i) * 64 + l] = x;
        }
        const f32x4* p2 = in + vslice + (size_t)(384 + w * 8) * 64 + l;   // rows 384-511
#pragma unroll
        for (int i = 0; i < 8; ++i) acc += p2[(size_t)i * 64];            // allocating: want L2
    }
    red[t] = acc;
    __syncthreads();
    if (t < 64) {                           // column-disjoint read-then-write: safe
        f32x4 r = {0.f, 0.f, 0.f, 0.f};
#pragma unroll
        for (int q = 0; q < 16; ++q) r += red[q * 64 + t];
        red[t] = r;
    }
    __syncthreads();
    const f32x4 vs = red[l];

    // ---- Phase B: stream u once (NT), gate vs vsum, accumulate usum ----
    f32x4 uacc = {0.f, 0.f, 0.f, 0.f};
    {
        const f32x4* pu = in  + uslice + (size_t)(w * 32) * 64 + l;
        f32x4*       po = out + uslice + (size_t)(w * 32) * 64 + l;
#pragma unroll 4
        for (int i = 0; i < 32; ++i) {
            f32x4 uv = __builtin_nontemporal_load(pu + (size_t)i * 64);
            uacc += uv;
            const float g = row_gate(uv, vs);
            __builtin_nontemporal_store(uv * g, po + (size_t)i * 64);
        }
    }
    __syncthreads();                        // all reads of red (vs) complete
    red[t] = uacc;
    __syncthreads();
    if (t < 64) {
        f32x4 r = {0.f, 0.f, 0.f, 0.f};
#pragma unroll
        for (int q = 0; q < 16; ++q) r += red[q * 64 + t];
        red[t] = r;
    }
    __syncthreads();
    const f32x4 us = red[l];

    // ---- Phase C: gate v from regs + LDS + L2 re-read; NT store ----
    {
        f32x4* po = out + vslice + (size_t)(w * 16) * 64 + l;             // rows 0-255
#pragma unroll
        for (int i = 0; i < 16; ++i) {
            const float g = row_gate(vreg[i], us);
            __builtin_nontemporal_store(vreg[i] * g, po + (size_t)i * 64);
        }
    }
    {
        f32x4* po = out + vslice + (size_t)(256 + w * 8) * 64 + l;        // rows 256-383
#pragma unroll
        for (int i = 0; i < 8; ++i) {
            f32x4 vv = vlds[(w * 8 + i) * 64 + l];
            const float g = row_gate(vv, us);
            __builtin_nontemporal_store(vv * g, po + (size_t)i * 64);
        }
    }
    {
        const f32x4* p2 = in  + vslice + (size_t)(384 + w * 8) * 64 + l;  // rows 384-511
        f32x4*       po = out + vslice + (size_t)(384 + w * 8) * 64 + l;
#pragma unroll
        for (int i = 0; i < 8; ++i) {
            f32x4 vv = p2[(size_t)i * 64];                                // L2 hit expected
            const float g = row_gate(vv, us);
            __builtin_nontemporal_store(vv * g, po + (size_t)i * 64);
        }
    }
}

extern "C" void kernel_launch(void* const* d_in, const int* in_sizes, int n_in,
                              void* d_out, int out_size, void* d_ws, size_t ws_size,
                              hipStream_t stream) {
    const f32x4* in  = (const f32x4*)d_in[0];
    f32x4*       out = (f32x4*)d_out;

    // Allow >64 KiB dynamic LDS (gfx950 supports 160 KiB/WG; AITER/HK use it).
    // Not a stream op; safe under graph capture, idempotent.
    hipFuncSetAttribute((const void*)k_fat,
                        hipFuncAttributeMaxDynamicSharedMemorySize, LDS_BYTES);

    k_fat<<<NBLK, NTHR, LDS_BYTES, stream>>>(in, out);
}